// Round 1
// baseline (218.809 us; speedup 1.0000x reference)
//
#include <hip/hip_runtime.h>

typedef unsigned short u16;
typedef __attribute__((ext_vector_type(4))) float f32x4;
typedef __attribute__((ext_vector_type(8))) short bf16x8;
typedef __attribute__((ext_vector_type(4))) unsigned short u16x4;

#define BM 128
#define BN 128
#define BK 64
#define NKT 16      // 1024/64 K-tiles per expert
#define EPB 8       // experts per block-group
#define NSTEP (EPB*NKT)

__device__ __forceinline__ u16 f2bf(float f) {
  union { float f; unsigned u; } v; v.f = f;
  unsigned r = v.u + 0x7FFFu + ((v.u >> 16) & 1u);
  return (u16)(r >> 16);
}

// ---- kernel 1: x (f32) -> bf16 ----
__global__ __launch_bounds__(256) void k_cvt_x(const float* __restrict__ x, u16* __restrict__ xb) {
  int i = blockIdx.x * 256 + threadIdx.x;           // 4 elements per thread, exact cover
  f32x4 v = ((const f32x4*)x)[i];
  u16x4 o;
  o.x = f2bf(v.x); o.y = f2bf(v.y); o.z = f2bf(v.z); o.w = f2bf(v.w);
  ((u16x4*)xb)[i] = o;
}

// ---- kernel 2: W[m][k][n] f32 -> Wt[m][n][k] bf16 (64x64 LDS transpose) ----
__global__ __launch_bounds__(256) void k_tw(const float* __restrict__ W, u16* __restrict__ wt) {
  __shared__ float t[64][65];
  int bid = blockIdx.x;
  int e = bid >> 8, rem = bid & 255, kt = rem >> 4, nt = rem & 15;
  int tid = threadIdx.x;
  int c = tid & 63, r0 = tid >> 6;
  const float* src = W + (size_t)e * 1048576 + (size_t)(kt * 64) * 1024 + nt * 64;
  #pragma unroll
  for (int p = 0; p < 16; ++p) {
    int r = r0 + p * 4;
    t[r][c] = src[r * 1024 + c];
  }
  __syncthreads();
  u16* dst = wt + (size_t)e * 1048576 + (size_t)(nt * 64) * 1024 + kt * 64;
  #pragma unroll
  for (int p = 0; p < 16; ++p) {
    int r2 = r0 + p * 4;
    dst[r2 * 1024 + c] = f2bf(t[c][r2]);
  }
}

// ---- kernel 3: gates[b][m] = gu^2 / sum_m gu^2, gu = x@Wg + bg ----
__global__ __launch_bounds__(256) void k_gates(const float* __restrict__ x, const float* __restrict__ Wg,
                                               const float* __restrict__ bg, float* __restrict__ gates) {
  int wid = threadIdx.x >> 6, lane = threadIdx.x & 63;
  int b = blockIdx.x * 4 + wid;
  const float* xr = x + (size_t)b * 1024;
  float acc[16];
  #pragma unroll
  for (int m = 0; m < 16; ++m) acc[m] = 0.f;
  for (int i = lane; i < 1024; i += 64) {
    float xv = xr[i];
    const f32x4* wg = (const f32x4*)(Wg + (size_t)i * 16);
    #pragma unroll
    for (int q = 0; q < 4; ++q) {
      f32x4 w = wg[q];
      acc[q*4+0] += xv * w.x; acc[q*4+1] += xv * w.y;
      acc[q*4+2] += xv * w.z; acc[q*4+3] += xv * w.w;
    }
  }
  #pragma unroll
  for (int m = 0; m < 16; ++m) {
    #pragma unroll
    for (int off = 32; off > 0; off >>= 1)
      acc[m] += __shfl_xor(acc[m], off, 64);
  }
  float tot = 0.f, gp[16];
  #pragma unroll
  for (int m = 0; m < 16; ++m) { float gu = acc[m] + bg[m]; gp[m] = gu * gu; tot += gp[m]; }
  float inv = 1.f / tot;
  if (lane == 0) {
    #pragma unroll
    for (int m = 0; m < 16; ++m) gates[(size_t)b * 16 + m] = gp[m] * inv;
  }
}

// ---- kernel 4: fused MoE GEMM ----
__global__ __launch_bounds__(256, 2)
void k_moe(const u16* __restrict__ xb, const u16* __restrict__ wt,
           const float* __restrict__ gates, const float* __restrict__ bias,
           float* __restrict__ out0, float* __restrict__ out1) {
  __shared__ __align__(16) u16 lsA[2][BM * BK];
  __shared__ __align__(16) u16 lsB[2][BN * BK];
  __shared__ float lgat[16][128];

  int tid = threadIdx.x;
  int bid = blockIdx.x;
  // XCD-chunked swizzle: each XCD gets 64 consecutive swz = all 32 btiles x 2 groups
  int swz = (bid & 7) * 64 + (bid >> 3);
  int btile = swz & 31;
  int grp = swz >> 5;
  int ntile = grp >> 1;
  int mhalf = grp & 1;
  int brow0 = btile * BM;
  int ncol0 = ntile * BN;
  int mb = mhalf * EPB;

  // stage this block's gates into LDS, transposed to [m][row]
  {
    const float* gsrc = gates + (size_t)brow0 * 16;
    #pragma unroll
    for (int i = 0; i < 8; ++i) {
      int idx = i * 256 + tid;
      lgat[idx & 15][idx >> 4] = gsrc[idx];
    }
  }

  int wid = tid >> 6, lane = tid & 63;
  int wm = wid >> 1, wn = wid & 1;
  int lrow = lane & 15, lk = lane >> 4;
  int sw = lrow & 7;

  f32x4 acc[4][4], oacc[4][4];
  #pragma unroll
  for (int i = 0; i < 4; ++i)
    #pragma unroll
    for (int j = 0; j < 4; ++j) {
      f32x4 z; z.x = 0.f; z.y = 0.f; z.z = 0.f; z.w = 0.f;
      acc[i][j] = z; oacc[i][j] = z;
    }

  const u16* asrc = xb + (size_t)brow0 * 1024;

  // stage a 128x64 bf16 tile (row stride 1024 elems) with inverse-swizzled global source
  auto stage = [&](const u16* src, u16* dst) {
    #pragma unroll
    for (int it = 0; it < 4; ++it) {
      int idx = it * 256 + tid;       // 0..1023 : 16B granules
      int r = idx >> 3, s = idx & 7;
      int g = s ^ (r & 7);            // logical granule living at physical slot s
      const u16* ga = src + (size_t)r * 1024 + g * 8;
      u16* la = dst + (size_t)(it * 256 + wid * 64) * 8;   // wave-uniform base
      __builtin_amdgcn_global_load_lds((const __attribute__((address_space(1))) void*)ga,
                                       (__attribute__((address_space(3))) void*)la, 16, 0, 0);
    }
  };

  int abase = (wm * 64 + lrow) * 64;
  int bbase = (wn * 64 + lrow) * 64;

  stage(asrc, lsA[0]);
  stage(wt + (size_t)mb * 1048576 + (size_t)ncol0 * 1024, lsB[0]);
  __syncthreads();

  int cur = 0;
  for (int s = 0; s < NSTEP; ++s) {
    int ns = s + 1;
    if (ns < NSTEP) {
      int kt = ns & (NKT - 1);
      int me = mb + (ns >> 4);
      stage(asrc + kt * BK, lsA[cur ^ 1]);
      stage(wt + (size_t)me * 1048576 + (size_t)ncol0 * 1024 + kt * BK, lsB[cur ^ 1]);
    }
    #pragma unroll
    for (int ks = 0; ks < 2; ++ks) {
      int kg = ((ks * 4 + lk) ^ sw) * 8;    // swizzled ds_read granule
      bf16x8 af[4], bfr[4];
      #pragma unroll
      for (int i = 0; i < 4; ++i) {
        af[i]  = *(const bf16x8*)&lsA[cur][abase + i * 1024 + kg];
        bfr[i] = *(const bf16x8*)&lsB[cur][bbase + i * 1024 + kg];
      }
      #pragma unroll
      for (int mi = 0; mi < 4; ++mi)
        #pragma unroll
        for (int ni = 0; ni < 4; ++ni)
          acc[mi][ni] = __builtin_amdgcn_mfma_f32_16x16x32_bf16(af[mi], bfr[ni], acc[mi][ni], 0, 0, 0);
    }
    __syncthreads();
    if ((s & (NKT - 1)) == (NKT - 1)) {
      int me = mb + (s >> 4);   // finished expert: relu + bias + gate, accumulate
      float bv[4];
      #pragma unroll
      for (int ni = 0; ni < 4; ++ni) bv[ni] = bias[(size_t)me * 1024 + ncol0 + wn * 64 + ni * 16 + lrow];
      #pragma unroll
      for (int mi = 0; mi < 4; ++mi) {
        float gv[4];
        #pragma unroll
        for (int j = 0; j < 4; ++j) gv[j] = lgat[me][wm * 64 + mi * 16 + lk * 4 + j];
        #pragma unroll
        for (int ni = 0; ni < 4; ++ni) {
          #pragma unroll
          for (int j = 0; j < 4; ++j) {
            float h = acc[mi][ni][j] + bv[ni];
            h = fmaxf(h, 0.f);
            oacc[mi][ni][j] += gv[j] * h;
          }
          f32x4 z; z.x = 0.f; z.y = 0.f; z.z = 0.f; z.w = 0.f;
          acc[mi][ni] = z;
        }
      }
    }
    cur ^= 1;
  }

  float* op = mhalf ? out1 : out0;
  #pragma unroll
  for (int mi = 0; mi < 4; ++mi)
    #pragma unroll
    for (int j = 0; j < 4; ++j) {
      int row = brow0 + wm * 64 + mi * 16 + lk * 4 + j;
      #pragma unroll
      for (int ni = 0; ni < 4; ++ni) {
        int col = ncol0 + wn * 64 + ni * 16 + lrow;
        op[(size_t)row * 1024 + col] = oacc[mi][ni][j];
      }
    }
}

// ---- kernel 5: out += p1 ----
__global__ __launch_bounds__(256) void k_add(float* __restrict__ out, const float* __restrict__ p1) {
  int i = blockIdx.x * 256 + threadIdx.x;
  f32x4 a = ((const f32x4*)out)[i];
  f32x4 b = ((const f32x4*)p1)[i];
  ((f32x4*)out)[i] = a + b;
}

extern "C" void kernel_launch(void* const* d_in, const int* in_sizes, int n_in,
                              void* d_out, int out_size, void* d_ws, size_t ws_size,
                              hipStream_t stream) {
  const float* x  = (const float*)d_in[0];   // [4096][1024]
  const float* W  = (const float*)d_in[1];   // [16][1024][1024]
  const float* b  = (const float*)d_in[2];   // [16][1024]
  const float* Wg = (const float*)d_in[3];   // [1024][16]
  const float* bg = (const float*)d_in[4];   // [16]
  float* out = (float*)d_out;                // [4096][1024]

  char* ws = (char*)d_ws;
  u16* xb     = (u16*)ws;                      // 8,388,608 B
  u16* wt     = (u16*)(ws + 8388608);          // 33,554,432 B
  float* gts  = (float*)(ws + 41943040);       // 262,144 B
  float* p1   = (float*)(ws + 42205184);       // 16,777,216 B  (total ~56.3 MB)

  k_cvt_x<<<4096, 256, 0, stream>>>(x, xb);
  k_tw<<<4096, 256, 0, stream>>>(W, wt);
  k_gates<<<1024, 256, 0, stream>>>(x, Wg, bg, gts);
  k_moe<<<512, 256, 0, stream>>>(xb, wt, gts, b, out, p1);
  k_add<<<4096, 256, 0, stream>>>(out, p1);
}

// Round 2
// 194.088 us; speedup vs baseline: 1.1274x; 1.1274x over previous
//
#include <hip/hip_runtime.h>

typedef unsigned short u16;
typedef __attribute__((ext_vector_type(4))) float f32x4;
typedef __attribute__((ext_vector_type(8))) short bf16x8;
typedef __attribute__((ext_vector_type(4))) unsigned short u16x4;

#define NT 128          // K-tiles per block: 8 experts x 16

__device__ __forceinline__ u16 f2bf(float f) {
  union { float f; unsigned u; } v; v.f = f;
  unsigned r = v.u + 0x7FFFu + ((v.u >> 16) & 1u);
  return (u16)(r >> 16);
}

__device__ __forceinline__ f32x4 zero4() {
  f32x4 z; z.x = 0.f; z.y = 0.f; z.z = 0.f; z.w = 0.f; return z;
}

// ---- kernel 1: x (f32) -> bf16 ----
__global__ __launch_bounds__(256) void k_cvt_x(const float* __restrict__ x, u16* __restrict__ xb) {
  int i = blockIdx.x * 256 + threadIdx.x;
  f32x4 v = ((const f32x4*)x)[i];
  u16x4 o;
  o.x = f2bf(v.x); o.y = f2bf(v.y); o.z = f2bf(v.z); o.w = f2bf(v.w);
  ((u16x4*)xb)[i] = o;
}

// ---- kernel 2: W[m][k][n] f32 -> Wt[m][n][k] bf16 (64x64 LDS transpose) ----
__global__ __launch_bounds__(256) void k_tw(const float* __restrict__ W, u16* __restrict__ wt) {
  __shared__ float t[64][65];
  int bid = blockIdx.x;
  int e = bid >> 8, rem = bid & 255, kt = rem >> 4, nt = rem & 15;
  int tid = threadIdx.x;
  int c = tid & 63, r0 = tid >> 6;
  const float* src = W + (size_t)e * 1048576 + (size_t)(kt * 64) * 1024 + nt * 64;
  #pragma unroll
  for (int p = 0; p < 16; ++p) {
    int r = r0 + p * 4;
    t[r][c] = src[r * 1024 + c];
  }
  __syncthreads();
  u16* dst = wt + (size_t)e * 1048576 + (size_t)(nt * 64) * 1024 + kt * 64;
  #pragma unroll
  for (int p = 0; p < 16; ++p) {
    int r2 = r0 + p * 4;
    dst[r2 * 1024 + c] = f2bf(t[c][r2]);
  }
}

// ---- kernel 3: gates[b][m] = gu^2 / sum_m gu^2, gu = x@Wg + bg ----
__global__ __launch_bounds__(256) void k_gates(const float* __restrict__ x, const float* __restrict__ Wg,
                                               const float* __restrict__ bg, float* __restrict__ gates) {
  int wid = threadIdx.x >> 6, lane = threadIdx.x & 63;
  int b = blockIdx.x * 4 + wid;
  const float* xr = x + (size_t)b * 1024;
  float acc[16];
  #pragma unroll
  for (int m = 0; m < 16; ++m) acc[m] = 0.f;
  for (int i = lane; i < 1024; i += 64) {
    float xv = xr[i];
    const f32x4* wg = (const f32x4*)(Wg + (size_t)i * 16);
    #pragma unroll
    for (int q = 0; q < 4; ++q) {
      f32x4 w = wg[q];
      acc[q*4+0] += xv * w.x; acc[q*4+1] += xv * w.y;
      acc[q*4+2] += xv * w.z; acc[q*4+3] += xv * w.w;
    }
  }
  #pragma unroll
  for (int m = 0; m < 16; ++m) {
    #pragma unroll
    for (int off = 32; off > 0; off >>= 1)
      acc[m] += __shfl_xor(acc[m], off, 64);
  }
  float tot = 0.f, gp[16];
  #pragma unroll
  for (int m = 0; m < 16; ++m) { float gu = acc[m] + bg[m]; gp[m] = gu * gu; tot += gp[m]; }
  float inv = 1.f / tot;
  if (lane == 0) {
    #pragma unroll
    for (int m = 0; m < 16; ++m) gates[(size_t)b * 16 + m] = gp[m] * inv;
  }
}

// ---- kernel 4: fused MoE GEMM, 128x256 tile, 8 waves, 4-phase/K-tile, 3-buf counted-vmcnt ----
#define GLL(srcaddr, ldsaddr) \
  __builtin_amdgcn_global_load_lds((const __attribute__((address_space(1))) void*)(srcaddr), \
                                   (__attribute__((address_space(3))) void*)(ldsaddr), 16, 0, 0)

#define MFMA8(m0) do { \
  acc[m0][0]   = __builtin_amdgcn_mfma_f32_16x16x32_bf16(af0, bfr0, acc[m0][0], 0,0,0);   \
  acc[m0][1]   = __builtin_amdgcn_mfma_f32_16x16x32_bf16(af0, bfr1, acc[m0][1], 0,0,0);   \
  acc[m0][2]   = __builtin_amdgcn_mfma_f32_16x16x32_bf16(af0, bfr2, acc[m0][2], 0,0,0);   \
  acc[m0][3]   = __builtin_amdgcn_mfma_f32_16x16x32_bf16(af0, bfr3, acc[m0][3], 0,0,0);   \
  acc[m0+1][0] = __builtin_amdgcn_mfma_f32_16x16x32_bf16(af1, bfr0, acc[m0+1][0], 0,0,0); \
  acc[m0+1][1] = __builtin_amdgcn_mfma_f32_16x16x32_bf16(af1, bfr1, acc[m0+1][1], 0,0,0); \
  acc[m0+1][2] = __builtin_amdgcn_mfma_f32_16x16x32_bf16(af1, bfr2, acc[m0+1][2], 0,0,0); \
  acc[m0+1][3] = __builtin_amdgcn_mfma_f32_16x16x32_bf16(af1, bfr3, acc[m0+1][3], 0,0,0); \
} while (0)

__global__ __launch_bounds__(512, 2)
void k_moe(const u16* __restrict__ xb, const u16* __restrict__ wt,
           const float* __restrict__ gates, const float* __restrict__ bias,
           float* __restrict__ out0, float* __restrict__ p1out) {
  __shared__ __align__(16) u16 sA[3 * 8192];    // 3 x 128x64 bf16
  __shared__ __align__(16) u16 sB[3 * 16384];   // 3 x 256x64 bf16
  __shared__ float lgat[1024];                  // [8 experts][128 rows]
  __shared__ float lbias[2048];                 // [8 experts][256 cols]

  int tid = threadIdx.x;
  int bid = blockIdx.x;
  // XCD-chunked swizzle: each XCD's 32 blocks share one (group,ntile) W-panel (4MB, fits L2)
  int swz = (bid & 7) * 32 + (bid >> 3);
  int btile = swz & 31;
  int pnl = swz >> 5;
  int grp = pnl >> 2;
  int ntile = pnl & 3;
  int brow0 = btile * 128;
  int ncol0 = ntile * 256;
  int mb = grp * 8;

  int wid = tid >> 6, lane = tid & 63;
  int wm = wid >> 2, wn = wid & 3;              // 2M x 4N wave grid, wave tile 64x64
  int lrow = lane & 15, lk = lane >> 4;
  int sw = lrow & 7;

  const u16* asrc = xb + (size_t)brow0 * 1024;
  const u16* bsrc = wt + (size_t)mb * 1048576 + (size_t)ncol0 * 1024;

  // per-lane stage offsets (inverse-swizzled global source, linear LDS dest)
  int r0a = tid >> 3, s0a = tid & 7;
  int r1a = (512 + tid) >> 3, s1a = tid & 7;
  int sia0 = r0a * 1024 + (s0a ^ (r0a & 7)) * 8;
  int sia1 = r1a * 1024 + (s1a ^ (r1a & 7)) * 8;
  int lda0 = (wid * 64) * 8;
  int lda1 = (512 + wid * 64) * 8;
  int sib0 = sia0, sib1 = sia1;
  int r2b = (1024 + tid) >> 3;
  int r3b = (1536 + tid) >> 3;
  int sib2 = r2b * 1024 + ((tid & 7) ^ (r2b & 7)) * 8;
  int sib3 = r3b * 1024 + ((tid & 7) ^ (r3b & 7)) * 8;
  int ldb0 = lda0, ldb1 = lda1;
  int ldb2 = (1024 + wid * 64) * 8;
  int ldb3 = (1536 + wid * 64) * 8;

  // frag read offsets (swizzled granules)
  int baseA = (wm * 64 + lrow) * 64;
  int baseB = (wn * 64 + lrow) * 64;
  int pa0 = baseA + ((0 + lk) ^ sw) * 8;   // kk=0
  int pa1 = baseA + ((4 + lk) ^ sw) * 8;   // kk=1
  int pb0 = baseB + ((0 + lk) ^ sw) * 8;
  int pb1 = baseB + ((4 + lk) ^ sw) * 8;

  f32x4 acc[4][4], oacc[4][4];
  #pragma unroll
  for (int i = 0; i < 4; ++i)
    #pragma unroll
    for (int j = 0; j < 4; ++j) { acc[i][j] = zero4(); oacc[i][j] = zero4(); }

  // prologue: gates+bias -> LDS; stage K-tiles 0,1
  #pragma unroll
  for (int i = 0; i < 2; ++i) {
    int idx = i * 512 + tid;
    lgat[idx] = gates[(size_t)(brow0 + (idx & 127)) * 16 + mb + (idx >> 7)];
  }
  #pragma unroll
  for (int i = 0; i < 4; ++i) {
    int idx = i * 512 + tid;
    lbias[idx] = bias[(size_t)(mb + (idx >> 8)) * 1024 + ncol0 + (idx & 255)];
  }
  u16 *a0 = sA, *a1 = sA + 8192, *a2 = sA + 16384;
  u16 *b0 = sB, *b1 = sB + 16384, *b2 = sB + 32768;
  GLL(asrc + sia0, a0 + lda0); GLL(asrc + sia1, a0 + lda1);
  GLL(bsrc + sib0, b0 + ldb0); GLL(bsrc + sib1, b0 + ldb1);
  GLL(bsrc + sib2, b0 + ldb2); GLL(bsrc + sib3, b0 + ldb3);
  GLL(asrc + 64 + sia0, a1 + lda0); GLL(asrc + 64 + sia1, a1 + lda1);
  GLL(bsrc + 64 + sib0, b1 + ldb0); GLL(bsrc + 64 + sib1, b1 + ldb1);
  GLL(bsrc + 64 + sib2, b1 + ldb2); GLL(bsrc + 64 + sib3, b1 + ldb3);
  __syncthreads();

  for (int t = 0; t < NT; ++t) {
    int t2 = t + 2;
    const u16* sa2 = asrc + (t2 & 15) * 64;
    const u16* sb2 = bsrc + (size_t)(t2 >> 4) * 1048576 + (t2 & 15) * 64;
    bool pf = (t2 < NT);
    bf16x8 bfr0, bfr1, bfr2, bfr3, af0, af1;

    // ---- phase 0: kk=0, rows 0-1
    bfr0 = *(const bf16x8*)&b0[pb0];
    bfr1 = *(const bf16x8*)&b0[pb0 + 1024];
    bfr2 = *(const bf16x8*)&b0[pb0 + 2048];
    bfr3 = *(const bf16x8*)&b0[pb0 + 3072];
    af0 = *(const bf16x8*)&a0[pa0];
    af1 = *(const bf16x8*)&a0[pa0 + 1024];
    if (pf) { GLL(sa2 + sia0, a2 + lda0); GLL(sa2 + sia1, a2 + lda1); }
    __builtin_amdgcn_s_barrier();
    __builtin_amdgcn_s_setprio(1);
    MFMA8(0);
    __builtin_amdgcn_s_setprio(0);
    __builtin_amdgcn_s_barrier();

    // ---- phase 1: kk=0, rows 2-3
    af0 = *(const bf16x8*)&a0[pa0 + 2048];
    af1 = *(const bf16x8*)&a0[pa0 + 3072];
    if (pf) { GLL(sb2 + sib0, b2 + ldb0); GLL(sb2 + sib1, b2 + ldb1); }
    __builtin_amdgcn_s_barrier();
    __builtin_amdgcn_s_setprio(1);
    MFMA8(2);
    __builtin_amdgcn_s_setprio(0);
    __builtin_amdgcn_s_barrier();

    // ---- phase 2: kk=1, rows 0-1
    bfr0 = *(const bf16x8*)&b0[pb1];
    bfr1 = *(const bf16x8*)&b0[pb1 + 1024];
    bfr2 = *(const bf16x8*)&b0[pb1 + 2048];
    bfr3 = *(const bf16x8*)&b0[pb1 + 3072];
    af0 = *(const bf16x8*)&a0[pa1];
    af1 = *(const bf16x8*)&a0[pa1 + 1024];
    if (pf) { GLL(sb2 + sib2, b2 + ldb2); GLL(sb2 + sib3, b2 + ldb3); }
    __builtin_amdgcn_s_barrier();
    __builtin_amdgcn_s_setprio(1);
    MFMA8(0);
    __builtin_amdgcn_s_setprio(0);
    __builtin_amdgcn_s_barrier();

    // ---- phase 3: kk=1, rows 2-3
    af0 = *(const bf16x8*)&a0[pa1 + 2048];
    af1 = *(const bf16x8*)&a0[pa1 + 3072];
    __builtin_amdgcn_s_barrier();
    __builtin_amdgcn_s_setprio(1);
    MFMA8(2);
    __builtin_amdgcn_s_setprio(0);

    // expert boundary: relu + bias + gate into running oacc
    if ((t & 15) == 15) {
      int ml = t >> 4;
      float bvv[4];
      #pragma unroll
      for (int ni = 0; ni < 4; ++ni) bvv[ni] = lbias[ml * 256 + wn * 64 + ni * 16 + lrow];
      #pragma unroll
      for (int mi = 0; mi < 4; ++mi) {
        f32x4 gv = *(const f32x4*)&lgat[ml * 128 + wm * 64 + mi * 16 + lk * 4];
        #pragma unroll
        for (int ni = 0; ni < 4; ++ni) {
          #pragma unroll
          for (int j = 0; j < 4; ++j) {
            float h = acc[mi][ni][j] + bvv[ni];
            h = fmaxf(h, 0.f);
            oacc[mi][ni][j] += gv[j] * h;
          }
          acc[mi][ni] = zero4();
        }
      }
    }

    // counted vmcnt: keep tile t+2's 6 loads in flight, drain t+1's
    if (t < NT - 2)       asm volatile("s_waitcnt vmcnt(6)" ::: "memory");
    else if (t == NT - 2) asm volatile("s_waitcnt vmcnt(0)" ::: "memory");
    __builtin_amdgcn_s_barrier();
    __builtin_amdgcn_sched_barrier(0);   // pin next tile's ds_reads below this point

    u16* ta = a0; a0 = a1; a1 = a2; a2 = ta;
    u16* tb = b0; b0 = b1; b1 = b2; b2 = tb;
  }

  float* op = grp ? p1out : out0;
  #pragma unroll
  for (int mi = 0; mi < 4; ++mi)
    #pragma unroll
    for (int j = 0; j < 4; ++j) {
      int row = brow0 + wm * 64 + mi * 16 + lk * 4 + j;
      #pragma unroll
      for (int ni = 0; ni < 4; ++ni) {
        int col = ncol0 + wn * 64 + ni * 16 + lrow;
        op[(size_t)row * 1024 + col] = oacc[mi][ni][j];
      }
    }
}

// ---- kernel 5: out += p1 ----
__global__ __launch_bounds__(256) void k_add(float* __restrict__ out, const float* __restrict__ p1) {
  int i = blockIdx.x * 256 + threadIdx.x;
  f32x4 a = ((const f32x4*)out)[i];
  f32x4 b = ((const f32x4*)p1)[i];
  ((f32x4*)out)[i] = a + b;
}

extern "C" void kernel_launch(void* const* d_in, const int* in_sizes, int n_in,
                              void* d_out, int out_size, void* d_ws, size_t ws_size,
                              hipStream_t stream) {
  const float* x  = (const float*)d_in[0];   // [4096][1024]
  const float* W  = (const float*)d_in[1];   // [16][1024][1024]
  const float* b  = (const float*)d_in[2];   // [16][1024]
  const float* Wg = (const float*)d_in[3];   // [1024][16]
  const float* bg = (const float*)d_in[4];   // [16]
  float* out = (float*)d_out;                // [4096][1024]

  char* ws = (char*)d_ws;
  u16* xb     = (u16*)ws;                      // 8,388,608 B
  u16* wt     = (u16*)(ws + 8388608);          // 33,554,432 B
  float* gts  = (float*)(ws + 41943040);       // 262,144 B
  float* p1   = (float*)(ws + 42205184);       // 16,777,216 B

  k_cvt_x<<<4096, 256, 0, stream>>>(x, xb);
  k_tw<<<4096, 256, 0, stream>>>(W, wt);
  k_gates<<<1024, 256, 0, stream>>>(x, Wg, bg, gts);
  k_moe<<<256, 512, 0, stream>>>(xb, wt, gts, b, out, p1);
  k_add<<<4096, 256, 0, stream>>>(out, p1);
}

// Round 3
// 193.460 us; speedup vs baseline: 1.1310x; 1.0032x over previous
//
#include <hip/hip_runtime.h>

typedef unsigned short u16;
typedef __attribute__((ext_vector_type(4))) float f32x4;
typedef __attribute__((ext_vector_type(8))) short bf16x8;
typedef __attribute__((ext_vector_type(4))) unsigned short u16x4;

#define NT 128          // K-tiles per block: 8 experts x 16

__device__ __forceinline__ u16 f2bf(float f) {
  union { float f; unsigned u; } v; v.f = f;
  unsigned r = v.u + 0x7FFFu + ((v.u >> 16) & 1u);
  return (u16)(r >> 16);
}

__device__ __forceinline__ f32x4 zero4() {
  f32x4 z; z.x = 0.f; z.y = 0.f; z.z = 0.f; z.w = 0.f; return z;
}

// ---- kernel 1: x (f32) -> bf16 ----
__global__ __launch_bounds__(256) void k_cvt_x(const float* __restrict__ x, u16* __restrict__ xb) {
  int i = blockIdx.x * 256 + threadIdx.x;
  f32x4 v = ((const f32x4*)x)[i];
  u16x4 o;
  o.x = f2bf(v.x); o.y = f2bf(v.y); o.z = f2bf(v.z); o.w = f2bf(v.w);
  ((u16x4*)xb)[i] = o;
}

// ---- kernel 2: W[m][k][n] f32 -> Wt[m][n][k] bf16 (64x64 LDS transpose) ----
__global__ __launch_bounds__(256) void k_tw(const float* __restrict__ W, u16* __restrict__ wt) {
  __shared__ float t[64][65];
  int bid = blockIdx.x;
  int e = bid >> 8, rem = bid & 255, kt = rem >> 4, nt = rem & 15;
  int tid = threadIdx.x;
  int c = tid & 63, r0 = tid >> 6;
  const float* src = W + (size_t)e * 1048576 + (size_t)(kt * 64) * 1024 + nt * 64;
  #pragma unroll
  for (int p = 0; p < 16; ++p) {
    int r = r0 + p * 4;
    t[r][c] = src[r * 1024 + c];
  }
  __syncthreads();
  u16* dst = wt + (size_t)e * 1048576 + (size_t)(nt * 64) * 1024 + kt * 64;
  #pragma unroll
  for (int p = 0; p < 16; ++p) {
    int r2 = r0 + p * 4;
    dst[r2 * 1024 + c] = f2bf(t[c][r2]);
  }
}

// ---- kernel 3: gates[b][m] = gu^2 / sum_m gu^2, gu = x@Wg + bg ----
__global__ __launch_bounds__(256) void k_gates(const float* __restrict__ x, const float* __restrict__ Wg,
                                               const float* __restrict__ bg, float* __restrict__ gates) {
  int wid = threadIdx.x >> 6, lane = threadIdx.x & 63;
  int b = blockIdx.x * 4 + wid;
  const float* xr = x + (size_t)b * 1024;
  float acc[16];
  #pragma unroll
  for (int m = 0; m < 16; ++m) acc[m] = 0.f;
  for (int i = lane; i < 1024; i += 64) {
    float xv = xr[i];
    const f32x4* wg = (const f32x4*)(Wg + (size_t)i * 16);
    #pragma unroll
    for (int q = 0; q < 4; ++q) {
      f32x4 w = wg[q];
      acc[q*4+0] += xv * w.x; acc[q*4+1] += xv * w.y;
      acc[q*4+2] += xv * w.z; acc[q*4+3] += xv * w.w;
    }
  }
  #pragma unroll
  for (int m = 0; m < 16; ++m) {
    #pragma unroll
    for (int off = 32; off > 0; off >>= 1)
      acc[m] += __shfl_xor(acc[m], off, 64);
  }
  float tot = 0.f, gp[16];
  #pragma unroll
  for (int m = 0; m < 16; ++m) { float gu = acc[m] + bg[m]; gp[m] = gu * gu; tot += gp[m]; }
  float inv = 1.f / tot;
  if (lane == 0) {
    #pragma unroll
    for (int m = 0; m < 16; ++m) gates[(size_t)b * 16 + m] = gp[m] * inv;
  }
}

// ---- kernel 4: fused MoE GEMM, 128x256 tile, 8 waves, 2-phase/K-tile, 3-buf counted-vmcnt ----
#define GLL(srcaddr, ldsaddr) \
  __builtin_amdgcn_global_load_lds((const __attribute__((address_space(1))) void*)(srcaddr), \
                                   (__attribute__((address_space(3))) void*)(ldsaddr), 16, 0, 0)

#define MFMA16() do { \
  acc[0][0] = __builtin_amdgcn_mfma_f32_16x16x32_bf16(af0, bfr0, acc[0][0], 0,0,0); \
  acc[0][1] = __builtin_amdgcn_mfma_f32_16x16x32_bf16(af0, bfr1, acc[0][1], 0,0,0); \
  acc[0][2] = __builtin_amdgcn_mfma_f32_16x16x32_bf16(af0, bfr2, acc[0][2], 0,0,0); \
  acc[0][3] = __builtin_amdgcn_mfma_f32_16x16x32_bf16(af0, bfr3, acc[0][3], 0,0,0); \
  acc[1][0] = __builtin_amdgcn_mfma_f32_16x16x32_bf16(af1, bfr0, acc[1][0], 0,0,0); \
  acc[1][1] = __builtin_amdgcn_mfma_f32_16x16x32_bf16(af1, bfr1, acc[1][1], 0,0,0); \
  acc[1][2] = __builtin_amdgcn_mfma_f32_16x16x32_bf16(af1, bfr2, acc[1][2], 0,0,0); \
  acc[1][3] = __builtin_amdgcn_mfma_f32_16x16x32_bf16(af1, bfr3, acc[1][3], 0,0,0); \
  acc[2][0] = __builtin_amdgcn_mfma_f32_16x16x32_bf16(af2, bfr0, acc[2][0], 0,0,0); \
  acc[2][1] = __builtin_amdgcn_mfma_f32_16x16x32_bf16(af2, bfr1, acc[2][1], 0,0,0); \
  acc[2][2] = __builtin_amdgcn_mfma_f32_16x16x32_bf16(af2, bfr2, acc[2][2], 0,0,0); \
  acc[2][3] = __builtin_amdgcn_mfma_f32_16x16x32_bf16(af2, bfr3, acc[2][3], 0,0,0); \
  acc[3][0] = __builtin_amdgcn_mfma_f32_16x16x32_bf16(af3, bfr0, acc[3][0], 0,0,0); \
  acc[3][1] = __builtin_amdgcn_mfma_f32_16x16x32_bf16(af3, bfr1, acc[3][1], 0,0,0); \
  acc[3][2] = __builtin_amdgcn_mfma_f32_16x16x32_bf16(af3, bfr2, acc[3][2], 0,0,0); \
  acc[3][3] = __builtin_amdgcn_mfma_f32_16x16x32_bf16(af3, bfr3, acc[3][3], 0,0,0); \
} while (0)

__global__ __launch_bounds__(512, 2)
void k_moe(const u16* __restrict__ xb, const u16* __restrict__ wt,
           const float* __restrict__ gates, const float* __restrict__ bias,
           float* __restrict__ out0, float* __restrict__ p1out) {
  __shared__ __align__(16) u16 sA[3 * 8192];    // 3 x 128x64 bf16
  __shared__ __align__(16) u16 sB[3 * 16384];   // 3 x 256x64 bf16
  __shared__ float lgat[1024];                  // [8 experts][128 rows]
  __shared__ float lbias[2048];                 // [8 experts][256 cols]

  int tid = threadIdx.x;
  int bid = blockIdx.x;
  // XCD-chunked swizzle: each XCD's 32 blocks share one (group,ntile) W-panel (4MB, fits L2)
  int swz = (bid & 7) * 32 + (bid >> 3);
  int btile = swz & 31;
  int pnl = swz >> 5;
  int grp = pnl >> 2;
  int ntile = pnl & 3;
  int brow0 = btile * 128;
  int ncol0 = ntile * 256;
  int mb = grp * 8;

  int wid = tid >> 6, lane = tid & 63;
  int wm = wid >> 2, wn = wid & 3;              // 2M x 4N wave grid, wave tile 64x64
  int lrow = lane & 15, lk = lane >> 4;
  int sw = lrow & 7;

  const u16* asrc = xb + (size_t)brow0 * 1024;
  const u16* bsrc = wt + (size_t)mb * 1048576 + (size_t)ncol0 * 1024;

  // per-lane stage offsets (inverse-swizzled global source, linear LDS dest)
  int r0a = tid >> 3, s0a = tid & 7;
  int r1a = (512 + tid) >> 3, s1a = tid & 7;
  int sia0 = r0a * 1024 + (s0a ^ (r0a & 7)) * 8;
  int sia1 = r1a * 1024 + (s1a ^ (r1a & 7)) * 8;
  int lda0 = (wid * 64) * 8;
  int lda1 = (512 + wid * 64) * 8;
  int sib0 = sia0, sib1 = sia1;
  int r2b = (1024 + tid) >> 3;
  int r3b = (1536 + tid) >> 3;
  int sib2 = r2b * 1024 + ((tid & 7) ^ (r2b & 7)) * 8;
  int sib3 = r3b * 1024 + ((tid & 7) ^ (r3b & 7)) * 8;
  int ldb0 = lda0, ldb1 = lda1;
  int ldb2 = (1024 + wid * 64) * 8;
  int ldb3 = (1536 + wid * 64) * 8;

  // frag read offsets (swizzled granules)
  int baseA = (wm * 64 + lrow) * 64;
  int baseB = (wn * 64 + lrow) * 64;
  int pa0 = baseA + ((0 + lk) ^ sw) * 8;   // kk=0
  int pa1 = baseA + ((4 + lk) ^ sw) * 8;   // kk=1
  int pb0 = baseB + ((0 + lk) ^ sw) * 8;
  int pb1 = baseB + ((4 + lk) ^ sw) * 8;

  f32x4 acc[4][4], oacc[4][4];
  #pragma unroll
  for (int i = 0; i < 4; ++i)
    #pragma unroll
    for (int j = 0; j < 4; ++j) { acc[i][j] = zero4(); oacc[i][j] = zero4(); }

  // prologue: gates+bias -> LDS; stage K-tiles 0,1
  #pragma unroll
  for (int i = 0; i < 2; ++i) {
    int idx = i * 512 + tid;
    lgat[idx] = gates[(size_t)(brow0 + (idx & 127)) * 16 + mb + (idx >> 7)];
  }
  #pragma unroll
  for (int i = 0; i < 4; ++i) {
    int idx = i * 512 + tid;
    lbias[idx] = bias[(size_t)(mb + (idx >> 8)) * 1024 + ncol0 + (idx & 255)];
  }
  u16 *a0 = sA, *a1 = sA + 8192, *a2 = sA + 16384;
  u16 *b0 = sB, *b1 = sB + 16384, *b2 = sB + 32768;
  GLL(asrc + sia0, a0 + lda0); GLL(asrc + sia1, a0 + lda1);
  GLL(bsrc + sib0, b0 + ldb0); GLL(bsrc + sib1, b0 + ldb1);
  GLL(bsrc + sib2, b0 + ldb2); GLL(bsrc + sib3, b0 + ldb3);
  GLL(asrc + 64 + sia0, a1 + lda0); GLL(asrc + 64 + sia1, a1 + lda1);
  GLL(bsrc + 64 + sib0, b1 + ldb0); GLL(bsrc + 64 + sib1, b1 + ldb1);
  GLL(bsrc + 64 + sib2, b1 + ldb2); GLL(bsrc + 64 + sib3, b1 + ldb3);
  __syncthreads();

  for (int t = 0; t < NT; ++t) {
    int t2 = t + 2;
    const u16* sa2 = asrc + (t2 & 15) * 64;
    const u16* sb2 = bsrc + (size_t)(t2 >> 4) * 1048576 + (t2 & 15) * 64;
    bool pf = (t2 < NT);
    bf16x8 bfr0, bfr1, bfr2, bfr3, af0, af1, af2, af3;

    // ---- phase 0: kk=0, full 4x4 (16 MFMA)
    af0  = *(const bf16x8*)&a0[pa0];
    af1  = *(const bf16x8*)&a0[pa0 + 1024];
    af2  = *(const bf16x8*)&a0[pa0 + 2048];
    af3  = *(const bf16x8*)&a0[pa0 + 3072];
    bfr0 = *(const bf16x8*)&b0[pb0];
    bfr1 = *(const bf16x8*)&b0[pb0 + 1024];
    bfr2 = *(const bf16x8*)&b0[pb0 + 2048];
    bfr3 = *(const bf16x8*)&b0[pb0 + 3072];
    if (pf) {
      GLL(sa2 + sia0, a2 + lda0); GLL(sa2 + sia1, a2 + lda1);
      GLL(sb2 + sib0, b2 + ldb0);
    }
    __builtin_amdgcn_s_barrier();
    __builtin_amdgcn_s_setprio(1);
    MFMA16();
    __builtin_amdgcn_s_setprio(0);
    __builtin_amdgcn_s_barrier();

    // ---- phase 1: kk=1, full 4x4 (16 MFMA)
    af0  = *(const bf16x8*)&a0[pa1];
    af1  = *(const bf16x8*)&a0[pa1 + 1024];
    af2  = *(const bf16x8*)&a0[pa1 + 2048];
    af3  = *(const bf16x8*)&a0[pa1 + 3072];
    bfr0 = *(const bf16x8*)&b0[pb1];
    bfr1 = *(const bf16x8*)&b0[pb1 + 1024];
    bfr2 = *(const bf16x8*)&b0[pb1 + 2048];
    bfr3 = *(const bf16x8*)&b0[pb1 + 3072];
    if (pf) {
      GLL(sb2 + sib1, b2 + ldb1);
      GLL(sb2 + sib2, b2 + ldb2);
      GLL(sb2 + sib3, b2 + ldb3);
    }
    __builtin_amdgcn_s_barrier();
    __builtin_amdgcn_s_setprio(1);
    MFMA16();
    __builtin_amdgcn_s_setprio(0);

    // expert boundary: relu + bias + gate into running oacc
    if ((t & 15) == 15) {
      int ml = t >> 4;
      float bvv[4];
      #pragma unroll
      for (int ni = 0; ni < 4; ++ni) bvv[ni] = lbias[ml * 256 + wn * 64 + ni * 16 + lrow];
      #pragma unroll
      for (int mi = 0; mi < 4; ++mi) {
        f32x4 gv = *(const f32x4*)&lgat[ml * 128 + wm * 64 + mi * 16 + lk * 4];
        #pragma unroll
        for (int ni = 0; ni < 4; ++ni) {
          #pragma unroll
          for (int j = 0; j < 4; ++j) {
            float h = acc[mi][ni][j] + bvv[ni];
            h = fmaxf(h, 0.f);
            oacc[mi][ni][j] += gv[j] * h;
          }
          acc[mi][ni] = zero4();
        }
      }
    }

    // counted vmcnt: keep tile t+2's 6 loads in flight, drain t+1's
    if (t < NT - 2)       asm volatile("s_waitcnt vmcnt(6)" ::: "memory");
    else if (t == NT - 2) asm volatile("s_waitcnt vmcnt(0)" ::: "memory");
    __builtin_amdgcn_s_barrier();
    __builtin_amdgcn_sched_barrier(0);   // pin next tile's ds_reads below this point

    u16* ta = a0; a0 = a1; a1 = a2; a2 = ta;
    u16* tb = b0; b0 = b1; b1 = b2; b2 = tb;
  }

  float* op = grp ? p1out : out0;
  #pragma unroll
  for (int mi = 0; mi < 4; ++mi)
    #pragma unroll
    for (int j = 0; j < 4; ++j) {
      int row = brow0 + wm * 64 + mi * 16 + lk * 4 + j;
      #pragma unroll
      for (int ni = 0; ni < 4; ++ni) {
        int col = ncol0 + wn * 64 + ni * 16 + lrow;
        op[(size_t)row * 1024 + col] = oacc[mi][ni][j];
      }
    }
}

// ---- kernel 5: out += p1 ----
__global__ __launch_bounds__(256) void k_add(float* __restrict__ out, const float* __restrict__ p1) {
  int i = blockIdx.x * 256 + threadIdx.x;
  f32x4 a = ((const f32x4*)out)[i];
  f32x4 b = ((const f32x4*)p1)[i];
  ((f32x4*)out)[i] = a + b;
}

extern "C" void kernel_launch(void* const* d_in, const int* in_sizes, int n_in,
                              void* d_out, int out_size, void* d_ws, size_t ws_size,
                              hipStream_t stream) {
  const float* x  = (const float*)d_in[0];   // [4096][1024]
  const float* W  = (const float*)d_in[1];   // [16][1024][1024]
  const float* b  = (const float*)d_in[2];   // [16][1024]
  const float* Wg = (const float*)d_in[3];   // [1024][16]
  const float* bg = (const float*)d_in[4];   // [16]
  float* out = (float*)d_out;                // [4096][1024]

  char* ws = (char*)d_ws;
  u16* xb     = (u16*)ws;                      // 8,388,608 B
  u16* wt     = (u16*)(ws + 8388608);          // 33,554,432 B
  float* gts  = (float*)(ws + 41943040);       // 262,144 B
  float* p1   = (float*)(ws + 42205184);       // 16,777,216 B

  k_cvt_x<<<4096, 256, 0, stream>>>(x, xb);
  k_tw<<<4096, 256, 0, stream>>>(W, wt);
  k_gates<<<1024, 256, 0, stream>>>(x, Wg, bg, gts);
  k_moe<<<256, 512, 0, stream>>>(xb, wt, gts, b, out, p1);
  k_add<<<4096, 256, 0, stream>>>(out, p1);
}

// Round 4
// 183.707 us; speedup vs baseline: 1.1911x; 1.0531x over previous
//
#include <hip/hip_runtime.h>

typedef unsigned short u16;
typedef __attribute__((ext_vector_type(4))) float f32x4;
typedef __attribute__((ext_vector_type(8))) short bf16x8;
typedef __attribute__((ext_vector_type(4))) unsigned short u16x4;

#define NT 128          // K-tiles per block: 8 experts x 16

__device__ __forceinline__ u16 f2bf(float f) {
  union { float f; unsigned u; } v; v.f = f;
  unsigned r = v.u + 0x7FFFu + ((v.u >> 16) & 1u);
  return (u16)(r >> 16);
}

__device__ __forceinline__ f32x4 zero4() {
  f32x4 z; z.x = 0.f; z.y = 0.f; z.z = 0.f; z.w = 0.f; return z;
}

// ---- kernel 1: x (f32) -> bf16 ----
__global__ __launch_bounds__(256) void k_cvt_x(const float* __restrict__ x, u16* __restrict__ xb) {
  int i = blockIdx.x * 256 + threadIdx.x;
  f32x4 v = ((const f32x4*)x)[i];
  u16x4 o;
  o.x = f2bf(v.x); o.y = f2bf(v.y); o.z = f2bf(v.z); o.w = f2bf(v.w);
  ((u16x4*)xb)[i] = o;
}

// ---- kernel 2: W[m][k][n] f32 -> Wt[m][n][k] bf16 (64x64 LDS transpose) ----
__global__ __launch_bounds__(256) void k_tw(const float* __restrict__ W, u16* __restrict__ wt) {
  __shared__ float t[64][65];
  int bid = blockIdx.x;
  int e = bid >> 8, rem = bid & 255, kt = rem >> 4, nt = rem & 15;
  int tid = threadIdx.x;
  int c = tid & 63, r0 = tid >> 6;
  const float* src = W + (size_t)e * 1048576 + (size_t)(kt * 64) * 1024 + nt * 64;
  #pragma unroll
  for (int p = 0; p < 16; ++p) {
    int r = r0 + p * 4;
    t[r][c] = src[r * 1024 + c];
  }
  __syncthreads();
  u16* dst = wt + (size_t)e * 1048576 + (size_t)(nt * 64) * 1024 + kt * 64;
  #pragma unroll
  for (int p = 0; p < 16; ++p) {
    int r2 = r0 + p * 4;
    dst[r2 * 1024 + c] = f2bf(t[c][r2]);
  }
}

// ---- kernel 3: gates[b][m] = gu^2 / sum_m gu^2, gu = x@Wg + bg ----
__global__ __launch_bounds__(256) void k_gates(const float* __restrict__ x, const float* __restrict__ Wg,
                                               const float* __restrict__ bg, float* __restrict__ gates) {
  int wid = threadIdx.x >> 6, lane = threadIdx.x & 63;
  int b = blockIdx.x * 4 + wid;
  const float* xr = x + (size_t)b * 1024;
  float acc[16];
  #pragma unroll
  for (int m = 0; m < 16; ++m) acc[m] = 0.f;
  for (int i = lane; i < 1024; i += 64) {
    float xv = xr[i];
    const f32x4* wg = (const f32x4*)(Wg + (size_t)i * 16);
    #pragma unroll
    for (int q = 0; q < 4; ++q) {
      f32x4 w = wg[q];
      acc[q*4+0] += xv * w.x; acc[q*4+1] += xv * w.y;
      acc[q*4+2] += xv * w.z; acc[q*4+3] += xv * w.w;
    }
  }
  #pragma unroll
  for (int m = 0; m < 16; ++m) {
    #pragma unroll
    for (int off = 32; off > 0; off >>= 1)
      acc[m] += __shfl_xor(acc[m], off, 64);
  }
  float tot = 0.f, gp[16];
  #pragma unroll
  for (int m = 0; m < 16; ++m) { float gu = acc[m] + bg[m]; gp[m] = gu * gu; tot += gp[m]; }
  float inv = 1.f / tot;
  if (lane == 0) {
    #pragma unroll
    for (int m = 0; m < 16; ++m) gates[(size_t)b * 16 + m] = gp[m] * inv;
  }
}

// ---- kernel 4: fused MoE GEMM, 128x256 tile, 8 waves, 1-barrier/K-tile, 3-buf counted-vmcnt ----
#define GLL(srcaddr, ldsaddr) \
  __builtin_amdgcn_global_load_lds((const __attribute__((address_space(1))) void*)(srcaddr), \
                                   (__attribute__((address_space(3))) void*)(ldsaddr), 16, 0, 0)

#define MFMA16(A0,A1,A2,A3,B0,B1,B2,B3) do { \
  acc[0][0] = __builtin_amdgcn_mfma_f32_16x16x32_bf16(A0, B0, acc[0][0], 0,0,0); \
  acc[0][1] = __builtin_amdgcn_mfma_f32_16x16x32_bf16(A0, B1, acc[0][1], 0,0,0); \
  acc[0][2] = __builtin_amdgcn_mfma_f32_16x16x32_bf16(A0, B2, acc[0][2], 0,0,0); \
  acc[0][3] = __builtin_amdgcn_mfma_f32_16x16x32_bf16(A0, B3, acc[0][3], 0,0,0); \
  acc[1][0] = __builtin_amdgcn_mfma_f32_16x16x32_bf16(A1, B0, acc[1][0], 0,0,0); \
  acc[1][1] = __builtin_amdgcn_mfma_f32_16x16x32_bf16(A1, B1, acc[1][1], 0,0,0); \
  acc[1][2] = __builtin_amdgcn_mfma_f32_16x16x32_bf16(A1, B2, acc[1][2], 0,0,0); \
  acc[1][3] = __builtin_amdgcn_mfma_f32_16x16x32_bf16(A1, B3, acc[1][3], 0,0,0); \
  acc[2][0] = __builtin_amdgcn_mfma_f32_16x16x32_bf16(A2, B0, acc[2][0], 0,0,0); \
  acc[2][1] = __builtin_amdgcn_mfma_f32_16x16x32_bf16(A2, B1, acc[2][1], 0,0,0); \
  acc[2][2] = __builtin_amdgcn_mfma_f32_16x16x32_bf16(A2, B2, acc[2][2], 0,0,0); \
  acc[2][3] = __builtin_amdgcn_mfma_f32_16x16x32_bf16(A2, B3, acc[2][3], 0,0,0); \
  acc[3][0] = __builtin_amdgcn_mfma_f32_16x16x32_bf16(A3, B0, acc[3][0], 0,0,0); \
  acc[3][1] = __builtin_amdgcn_mfma_f32_16x16x32_bf16(A3, B1, acc[3][1], 0,0,0); \
  acc[3][2] = __builtin_amdgcn_mfma_f32_16x16x32_bf16(A3, B2, acc[3][2], 0,0,0); \
  acc[3][3] = __builtin_amdgcn_mfma_f32_16x16x32_bf16(A3, B3, acc[3][3], 0,0,0); \
} while (0)

__global__ __launch_bounds__(512, 2)
void k_moe(const u16* __restrict__ xb, const u16* __restrict__ wt,
           const float* __restrict__ gates, const float* __restrict__ bias,
           float* __restrict__ out0, float* __restrict__ p1out) {
  __shared__ __align__(16) u16 sA[3 * 8192];    // 3 x 128x64 bf16
  __shared__ __align__(16) u16 sB[3 * 16384];   // 3 x 256x64 bf16
  __shared__ float lgat[1024];                  // [8 experts][128 rows]
  __shared__ float lbias[2048];                 // [8 experts][256 cols]

  int tid = threadIdx.x;
  int bid = blockIdx.x;
  // XCD-chunked swizzle: each XCD's 32 blocks share one (group,ntile) W-panel (4MB, fits L2)
  int swz = (bid & 7) * 32 + (bid >> 3);
  int btile = swz & 31;
  int pnl = swz >> 5;
  int grp = pnl >> 2;
  int ntile = pnl & 3;
  int brow0 = btile * 128;
  int ncol0 = ntile * 256;
  int mb = grp * 8;

  int wid = tid >> 6, lane = tid & 63;
  int wm = wid >> 2, wn = wid & 3;              // 2M x 4N wave grid, wave tile 64x64
  int lrow = lane & 15, lk = lane >> 4;
  int sw = lrow & 7;

  const u16* asrc = xb + (size_t)brow0 * 1024;
  const u16* bsrc = wt + (size_t)mb * 1048576 + (size_t)ncol0 * 1024;

  // per-lane stage offsets (inverse-swizzled global source, linear LDS dest)
  int r0a = tid >> 3, s0a = tid & 7;
  int r1a = (512 + tid) >> 3, s1a = tid & 7;
  int sia0 = r0a * 1024 + (s0a ^ (r0a & 7)) * 8;
  int sia1 = r1a * 1024 + (s1a ^ (r1a & 7)) * 8;
  int lda0 = (wid * 64) * 8;
  int lda1 = (512 + wid * 64) * 8;
  int sib0 = sia0, sib1 = sia1;
  int r2b = (1024 + tid) >> 3;
  int r3b = (1536 + tid) >> 3;
  int sib2 = r2b * 1024 + ((tid & 7) ^ (r2b & 7)) * 8;
  int sib3 = r3b * 1024 + ((tid & 7) ^ (r3b & 7)) * 8;
  int ldb0 = lda0, ldb1 = lda1;
  int ldb2 = (1024 + wid * 64) * 8;
  int ldb3 = (1536 + wid * 64) * 8;

  // frag read offsets (swizzled granules)
  int baseA = (wm * 64 + lrow) * 64;
  int baseB = (wn * 64 + lrow) * 64;
  int pa0 = baseA + ((0 + lk) ^ sw) * 8;   // kk=0
  int pa1 = baseA + ((4 + lk) ^ sw) * 8;   // kk=1
  int pb0 = baseB + ((0 + lk) ^ sw) * 8;
  int pb1 = baseB + ((4 + lk) ^ sw) * 8;

  f32x4 acc[4][4], oacc[4][4];
  #pragma unroll
  for (int i = 0; i < 4; ++i)
    #pragma unroll
    for (int j = 0; j < 4; ++j) { acc[i][j] = zero4(); oacc[i][j] = zero4(); }

  // prologue: gates+bias -> LDS; stage K-tiles 0,1
  #pragma unroll
  for (int i = 0; i < 2; ++i) {
    int idx = i * 512 + tid;
    lgat[idx] = gates[(size_t)(brow0 + (idx & 127)) * 16 + mb + (idx >> 7)];
  }
  #pragma unroll
  for (int i = 0; i < 4; ++i) {
    int idx = i * 512 + tid;
    lbias[idx] = bias[(size_t)(mb + (idx >> 8)) * 1024 + ncol0 + (idx & 255)];
  }
  u16 *a0 = sA, *a1 = sA + 8192, *a2 = sA + 16384;
  u16 *b0 = sB, *b1 = sB + 16384, *b2 = sB + 32768;
  GLL(asrc + sia0, a0 + lda0); GLL(asrc + sia1, a0 + lda1);
  GLL(bsrc + sib0, b0 + ldb0); GLL(bsrc + sib1, b0 + ldb1);
  GLL(bsrc + sib2, b0 + ldb2); GLL(bsrc + sib3, b0 + ldb3);
  GLL(asrc + 64 + sia0, a1 + lda0); GLL(asrc + 64 + sia1, a1 + lda1);
  GLL(bsrc + 64 + sib0, b1 + ldb0); GLL(bsrc + 64 + sib1, b1 + ldb1);
  GLL(bsrc + 64 + sib2, b1 + ldb2); GLL(bsrc + 64 + sib3, b1 + ldb3);
  // tile 0 resident (tile 1's 6 loads stay in flight), then sync LDS writes
  asm volatile("s_waitcnt vmcnt(6)" ::: "memory");
  __builtin_amdgcn_s_barrier();
  __builtin_amdgcn_sched_barrier(0);

  for (int t = 0; t < NT; ++t) {
    int t2 = t + 2;
    const u16* sa2 = asrc + (t2 & 15) * 64;
    const u16* sb2 = bsrc + (size_t)(t2 >> 4) * 1048576 + (t2 & 15) * 64;
    bool pf = (t2 < NT);
    bf16x8 a00, a01, a02, a03, a10, a11, a12, a13;
    bf16x8 b00, b01, b02, b03, b10, b11, b12, b13;

    // all 16 fragment reads up front; compiler pipelines lgkmcnt + interleaves with MFMA
    a00 = *(const bf16x8*)&a0[pa0];
    a01 = *(const bf16x8*)&a0[pa0 + 1024];
    a02 = *(const bf16x8*)&a0[pa0 + 2048];
    a03 = *(const bf16x8*)&a0[pa0 + 3072];
    b00 = *(const bf16x8*)&b0[pb0];
    b01 = *(const bf16x8*)&b0[pb0 + 1024];
    b02 = *(const bf16x8*)&b0[pb0 + 2048];
    b03 = *(const bf16x8*)&b0[pb0 + 3072];
    a10 = *(const bf16x8*)&a0[pa1];
    a11 = *(const bf16x8*)&a0[pa1 + 1024];
    a12 = *(const bf16x8*)&a0[pa1 + 2048];
    a13 = *(const bf16x8*)&a0[pa1 + 3072];
    b10 = *(const bf16x8*)&b0[pb1];
    b11 = *(const bf16x8*)&b0[pb1 + 1024];
    b12 = *(const bf16x8*)&b0[pb1 + 2048];
    b13 = *(const bf16x8*)&b0[pb1 + 3072];

    if (pf) {
      GLL(sa2 + sia0, a2 + lda0); GLL(sa2 + sia1, a2 + lda1);
      GLL(sb2 + sib0, b2 + ldb0); GLL(sb2 + sib1, b2 + ldb1);
      GLL(sb2 + sib2, b2 + ldb2); GLL(sb2 + sib3, b2 + ldb3);
    }

    __builtin_amdgcn_s_setprio(1);
    MFMA16(a00, a01, a02, a03, b00, b01, b02, b03);
    MFMA16(a10, a11, a12, a13, b10, b11, b12, b13);
    __builtin_amdgcn_s_setprio(0);

    // expert boundary: relu + bias + gate into running oacc
    if ((t & 15) == 15) {
      int ml = t >> 4;
      float bvv[4];
      #pragma unroll
      for (int ni = 0; ni < 4; ++ni) bvv[ni] = lbias[ml * 256 + wn * 64 + ni * 16 + lrow];
      #pragma unroll
      for (int mi = 0; mi < 4; ++mi) {
        f32x4 gv = *(const f32x4*)&lgat[ml * 128 + wm * 64 + mi * 16 + lk * 4];
        #pragma unroll
        for (int ni = 0; ni < 4; ++ni) {
          #pragma unroll
          for (int j = 0; j < 4; ++j) {
            float h = acc[mi][ni][j] + bvv[ni];
            h = fmaxf(h, 0.f);
            oacc[mi][ni][j] += gv[j] * h;
          }
          acc[mi][ni] = zero4();
        }
      }
    }

    // counted vmcnt: keep tile t+2's 6 loads in flight, drain t+1's
    if (t < NT - 2)       asm volatile("s_waitcnt vmcnt(6)" ::: "memory");
    else if (t == NT - 2) asm volatile("s_waitcnt vmcnt(0)" ::: "memory");
    __builtin_amdgcn_s_barrier();
    __builtin_amdgcn_sched_barrier(0);   // pin next tile's ds_reads below this point

    u16* ta = a0; a0 = a1; a1 = a2; a2 = ta;
    u16* tb = b0; b0 = b1; b1 = b2; b2 = tb;
  }

  float* op = grp ? p1out : out0;
  #pragma unroll
  for (int mi = 0; mi < 4; ++mi)
    #pragma unroll
    for (int j = 0; j < 4; ++j) {
      int row = brow0 + wm * 64 + mi * 16 + lk * 4 + j;
      #pragma unroll
      for (int ni = 0; ni < 4; ++ni) {
        int col = ncol0 + wn * 64 + ni * 16 + lrow;
        op[(size_t)row * 1024 + col] = oacc[mi][ni][j];
      }
    }
}

// ---- kernel 5: out += p1 ----
__global__ __launch_bounds__(256) void k_add(float* __restrict__ out, const float* __restrict__ p1) {
  int i = blockIdx.x * 256 + threadIdx.x;
  f32x4 a = ((const f32x4*)out)[i];
  f32x4 b = ((const f32x4*)p1)[i];
  ((f32x4*)out)[i] = a + b;
}

extern "C" void kernel_launch(void* const* d_in, const int* in_sizes, int n_in,
                              void* d_out, int out_size, void* d_ws, size_t ws_size,
                              hipStream_t stream) {
  const float* x  = (const float*)d_in[0];   // [4096][1024]
  const float* W  = (const float*)d_in[1];   // [16][1024][1024]
  const float* b  = (const float*)d_in[2];   // [16][1024]
  const float* Wg = (const float*)d_in[3];   // [1024][16]
  const float* bg = (const float*)d_in[4];   // [16]
  float* out = (float*)d_out;                // [4096][1024]

  char* ws = (char*)d_ws;
  u16* xb     = (u16*)ws;                      // 8,388,608 B
  u16* wt     = (u16*)(ws + 8388608);          // 33,554,432 B
  float* gts  = (float*)(ws + 41943040);       // 262,144 B
  float* p1   = (float*)(ws + 42205184);       // 16,777,216 B

  k_cvt_x<<<4096, 256, 0, stream>>>(x, xb);
  k_tw<<<4096, 256, 0, stream>>>(W, wt);
  k_gates<<<1024, 256, 0, stream>>>(x, Wg, bg, gts);
  k_moe<<<256, 512, 0, stream>>>(xb, wt, gts, b, out, p1);
  k_add<<<4096, 256, 0, stream>>>(out, p1);
}